// Round 1
// baseline (876.851 us; speedup 1.0000x reference)
//
#include <hip/hip_runtime.h>
#include <math.h>

#define N_NODES 50000
#define E_EDGES 500000
#define F_IN    128
#define HDIM    128
#define OUTC    2
#define NGRAPH  512

// ---------------- utility: zero a span of 4-byte words ----------------
__global__ void k_zero(int* __restrict__ p, int n) {
    int i = blockIdx.x * blockDim.x + threadIdx.x;
    int stride = gridDim.x * blockDim.x;
    for (; i < n; i += stride) p[i] = 0;
}

// ---------------- edge histogram over dst ----------------
__global__ void k_hist(const int* __restrict__ dst, int* __restrict__ cnt) {
    int i = blockIdx.x * blockDim.x + threadIdx.x;
    int stride = gridDim.x * blockDim.x;
    for (; i < E_EDGES; i += stride) atomicAdd(&cnt[dst[i]], 1);
}

// ---------------- scan stage A: per-block exclusive scan of edge counts ----
// also computes dinv[i] = 1/sqrt(deg) (deg = in-edges + self-loop) and the
// per-graph node counts (for mean pooling).
__global__ void k_scan_a(const int* __restrict__ cnt, int* __restrict__ excl,
                         int* __restrict__ blksum, float* __restrict__ dinv,
                         const int* __restrict__ batch, float* __restrict__ cnt_g) {
    __shared__ int s[512];
    int t = threadIdx.x;
    int i = blockIdx.x * 512 + t;
    int v = 0;
    if (i < N_NODES) {
        v = cnt[i];
        dinv[i] = 1.0f / sqrtf((float)(v + 1));
        atomicAdd(&cnt_g[batch[i]], 1.0f);
    }
    s[t] = v; __syncthreads();
    for (int off = 1; off < 512; off <<= 1) {
        int add = (t >= off) ? s[t - off] : 0;
        __syncthreads();
        s[t] += add;
        __syncthreads();
    }
    if (i < N_NODES) excl[i] = s[t] - v;     // exclusive within block
    if (t == 511) blksum[blockIdx.x] = s[511];
}

// ---------------- scan stage B: exclusive scan of block sums (single block) --
__global__ void k_scan_b(int* __restrict__ blksum, int nb) {
    __shared__ int s[512];
    int t = threadIdx.x;
    int v = (t < nb) ? blksum[t] : 0;
    s[t] = v; __syncthreads();
    for (int off = 1; off < 512; off <<= 1) {
        int add = (t >= off) ? s[t - off] : 0;
        __syncthreads();
        s[t] += add;
        __syncthreads();
    }
    if (t < nb) blksum[t] = s[t] - v;        // exclusive, in place
}

// ---------------- scan stage C: add block offsets, finalize row_ptr --------
__global__ void k_scan_c(int* __restrict__ excl, const int* __restrict__ blksum) {
    int t = threadIdx.x;
    int i = blockIdx.x * 512 + t;
    if (i < N_NODES) excl[i] += blksum[blockIdx.x];
    if (i == 0) excl[N_NODES] = E_EDGES;
}

// ---------------- CSR fill: scatter src indices grouped by dst -------------
__global__ void k_fill(const int* __restrict__ src, const int* __restrict__ dst,
                       const int* __restrict__ row_ptr, int* __restrict__ fill_cnt,
                       int* __restrict__ src_sorted) {
    int i = blockIdx.x * blockDim.x + threadIdx.x;
    int stride = gridDim.x * blockDim.x;
    for (; i < E_EDGES; i += stride) {
        int d = dst[i];
        int p = atomicAdd(&fill_cnt[d], 1);
        src_sorted[row_ptr[d] + p] = src[i];
    }
}

// ---------------- generic fp32 GEMM: C = act(A@B + bias) -------------------
// A: MxK row-major (lda=K), B: KxN row-major (ldb=N), C row-major with ldc.
// BM=BN=64, BK=16, 256 threads, 4x4 micro-tile per thread. K % 16 == 0.
__global__ __launch_bounds__(256) void k_gemm(
        const float* __restrict__ A, const float* __restrict__ B,
        const float* __restrict__ bias, float* __restrict__ C,
        int M, int Nn, int K, int ldc, int act) {
    __shared__ float As[16][64];       // [k][m]
    __shared__ float Bs[16][68];       // [k][n] (+4 pad, keeps 16B align)
    int tid = threadIdx.x;
    int tx = tid & 15, ty = tid >> 4;
    int row0 = blockIdx.x * 64, col0 = blockIdx.y * 64;
    float acc[4][4] = {};
    int arow = tid >> 2;               // 0..63
    int acol = (tid & 3) * 4;          // 0,4,8,12
    int brow = tid >> 4;               // 0..15
    int bcol = (tid & 15) * 4;         // 0..60

    for (int k0 = 0; k0 < K; k0 += 16) {
        float4 av = make_float4(0.f, 0.f, 0.f, 0.f);
        int ar = row0 + arow;
        if (ar < M) av = *(const float4*)(A + (size_t)ar * K + k0 + acol);
        As[acol + 0][arow] = av.x;
        As[acol + 1][arow] = av.y;
        As[acol + 2][arow] = av.z;
        As[acol + 3][arow] = av.w;

        float4 bv = make_float4(0.f, 0.f, 0.f, 0.f);
        const float* Brow = B + (size_t)(k0 + brow) * Nn;
        int bc = col0 + bcol;
        if (bc + 3 < Nn) {
            bv = *(const float4*)(Brow + bc);
        } else {
            if (bc     < Nn) bv.x = Brow[bc];
            if (bc + 1 < Nn) bv.y = Brow[bc + 1];
            if (bc + 2 < Nn) bv.z = Brow[bc + 2];
        }
        Bs[brow][bcol + 0] = bv.x;
        Bs[brow][bcol + 1] = bv.y;
        Bs[brow][bcol + 2] = bv.z;
        Bs[brow][bcol + 3] = bv.w;
        __syncthreads();

#pragma unroll
        for (int k = 0; k < 16; k++) {
            float4 a = *(const float4*)&As[k][ty * 4];
            float4 b = *(const float4*)&Bs[k][tx * 4];
            acc[0][0] += a.x * b.x; acc[0][1] += a.x * b.y; acc[0][2] += a.x * b.z; acc[0][3] += a.x * b.w;
            acc[1][0] += a.y * b.x; acc[1][1] += a.y * b.y; acc[1][2] += a.y * b.z; acc[1][3] += a.y * b.w;
            acc[2][0] += a.z * b.x; acc[2][1] += a.z * b.y; acc[2][2] += a.z * b.z; acc[2][3] += a.z * b.w;
            acc[3][0] += a.w * b.x; acc[3][1] += a.w * b.y; acc[3][2] += a.w * b.z; acc[3][3] += a.w * b.w;
        }
        __syncthreads();
    }

#pragma unroll
    for (int i = 0; i < 4; i++) {
        int r = row0 + ty * 4 + i;
        if (r >= M) continue;
#pragma unroll
        for (int j = 0; j < 4; j++) {
            int c = col0 + tx * 4 + j;
            if (c >= Nn) continue;
            float v = acc[i][j];
            if (bias) v += bias[c];
            if (act) v = fmaxf(v, 0.0f);
            C[(size_t)r * ldc + c] = v;
        }
    }
}

// ---------------- CSR aggregation (one wave per node, float2 per lane) -----
// MODE 0: out[node] = relu(agg + bias)
// MODE 2: pool[batch[node]] += agg   (atomic; no bias, no relu)
template <int MODE>
__global__ __launch_bounds__(256) void k_agg(
        const float* __restrict__ Hin, const float* __restrict__ dinv,
        const int* __restrict__ row_ptr, const int* __restrict__ src_sorted,
        const float* __restrict__ bias, float* __restrict__ out,
        const int* __restrict__ batch, float* __restrict__ pool) {
    int wave = threadIdx.x >> 6, lane = threadIdx.x & 63;
    int node = blockIdx.x * 4 + wave;
    if (node >= N_NODES) return;

    float di = dinv[node];
    const float2* hr = (const float2*)(Hin + (size_t)node * HDIM);
    float2 hv = hr[lane];
    float ax = hv.x * di * di;          // self-loop term
    float ay = hv.y * di * di;

    int rs = row_ptr[node], re = row_ptr[node + 1];
    for (int base = rs; base < re; base += 64) {
        int e = base + lane;
        int s = 0; float w = 0.f;
        if (e < re) {
            s = src_sorted[e];
            w = dinv[s] * di;
        }
        int cnt = re - base; if (cnt > 64) cnt = 64;
        for (int j = 0; j < cnt; j++) {
            int   sj = __shfl(s, j);
            float wj = __shfl(w, j);
            const float2* sr = (const float2*)(Hin + (size_t)sj * HDIM);
            float2 sv = sr[lane];
            ax += sv.x * wj;
            ay += sv.y * wj;
        }
    }

    if (MODE == 2) {
        int g = batch[node];
        atomicAdd(pool + (size_t)g * HDIM + lane * 2,     ax);
        atomicAdd(pool + (size_t)g * HDIM + lane * 2 + 1, ay);
    } else {
        float ox = ax + bias[lane * 2];
        float oy = ay + bias[lane * 2 + 1];
        ox = fmaxf(ox, 0.0f);
        oy = fmaxf(oy, 0.0f);
        float2* orow = (float2*)(out + (size_t)node * HDIM);
        orow[lane] = make_float2(ox, oy);
    }
}

// ---------------- divide pooled sums by graph node counts ------------------
__global__ void k_divpool(float* __restrict__ pool, const float* __restrict__ cnt_g) {
    int i = blockIdx.x * blockDim.x + threadIdx.x;
    if (i < NGRAPH * HDIM) pool[i] /= fmaxf(cnt_g[i >> 7], 1.0f);
}

extern "C" void kernel_launch(void* const* d_in, const int* in_sizes, int n_in,
                              void* d_out, int out_size, void* d_ws, size_t ws_size,
                              hipStream_t stream) {
    (void)in_sizes; (void)n_in; (void)out_size; (void)ws_size;

    const float* x[2]  = {(const float*)d_in[0], (const float*)d_in[1]};
    const int*   ei[2] = {(const int*)d_in[2], (const int*)d_in[3]};
    const int*   bt[2] = {(const int*)d_in[4], (const int*)d_in[5]};
    const float* W1  = (const float*)d_in[6];  const float* b1  = (const float*)d_in[7];
    const float* W2  = (const float*)d_in[8];  const float* b2  = (const float*)d_in[9];
    const float* W3  = (const float*)d_in[10]; const float* b3  = (const float*)d_in[11];
    const float* Wc1 = (const float*)d_in[12]; const float* bc1 = (const float*)d_in[13];
    const float* Wc2 = (const float*)d_in[14]; const float* bc2 = (const float*)d_in[15];
    const float* Wc3 = (const float*)d_in[16]; const float* bc3 = (const float*)d_in[17];
    float* out = (float*)d_out;

    char* ws = (char*)d_ws;
    size_t off = 0;
    auto carve = [&](size_t bytes) -> char* {
        char* p = ws + off;
        off += (bytes + 255) & ~(size_t)255;
        return p;
    };

    // contiguous zero-group (zeroed once per side with one launch)
    int*   edge_cnt = (int*)  carve((size_t)N_NODES * 4);
    int*   fill_cnt = (int*)  carve((size_t)N_NODES * 4);
    float* pool_s   = (float*)carve((size_t)NGRAPH * HDIM * 4);
    float* cnt_g    = (float*)carve((size_t)NGRAPH * 4);
    int zero_words = (int)(((char*)(cnt_g + NGRAPH) - (char*)edge_cnt + 3) / 4);

    float* dinv       = (float*)carve((size_t)N_NODES * 4);
    int*   row_ptr    = (int*)  carve((size_t)(N_NODES + 1) * 4);
    int*   src_sorted = (int*)  carve((size_t)E_EDGES * 4);
    int*   blksum     = (int*)  carve(512 * 4);
    float* hA         = (float*)carve((size_t)N_NODES * HDIM * 4);
    float* hB         = (float*)carve((size_t)N_NODES * HDIM * 4);
    float* zcat       = (float*)carve((size_t)NGRAPH * 2 * HDIM * 4);
    float* z1         = (float*)carve((size_t)NGRAPH * 4 * HDIM * 4);
    float* z2         = (float*)carve((size_t)NGRAPH * 2 * HDIM * 4);

    const int nscan = (N_NODES + 511) / 512;            // 98 blocks
    const dim3 gemm_big((N_NODES + 63) / 64, HDIM / 64); // 782 x 2
    const int agg_blocks = (N_NODES + 3) / 4;            // 12500

    for (int s = 0; s < 2; ++s) {
        const int* esrc = ei[s];
        const int* edst = ei[s] + E_EDGES;

        k_zero<<<512, 256, 0, stream>>>(edge_cnt, zero_words);
        k_hist<<<512, 256, 0, stream>>>(edst, edge_cnt);
        k_scan_a<<<nscan, 512, 0, stream>>>(edge_cnt, row_ptr, blksum, dinv, bt[s], cnt_g);
        k_scan_b<<<1, 512, 0, stream>>>(blksum, nscan);
        k_scan_c<<<nscan, 512, 0, stream>>>(row_ptr, blksum);
        k_fill<<<512, 256, 0, stream>>>(esrc, edst, row_ptr, fill_cnt, src_sorted);

        // layer 1: hB = relu(agg(x @ W1) + b1)
        k_gemm<<<gemm_big, 256, 0, stream>>>(x[s], W1, nullptr, hA, N_NODES, HDIM, F_IN, HDIM, 0);
        k_agg<0><<<agg_blocks, 256, 0, stream>>>(hA, dinv, row_ptr, src_sorted, b1, hB, nullptr, nullptr);

        // layer 2: hB = relu(agg(hB @ W2) + b2)
        k_gemm<<<gemm_big, 256, 0, stream>>>(hB, W2, nullptr, hA, N_NODES, HDIM, HDIM, HDIM, 0);
        k_agg<0><<<agg_blocks, 256, 0, stream>>>(hA, dinv, row_ptr, src_sorted, b2, hB, nullptr, nullptr);

        // layer 3 (reordered): pool_s = segment_sum(agg(hB)); mean; then @W3+b3
        k_agg<2><<<agg_blocks, 256, 0, stream>>>(hB, dinv, row_ptr, src_sorted, nullptr, nullptr, bt[s], pool_s);
        k_divpool<<<(NGRAPH * HDIM + 255) / 256, 256, 0, stream>>>(pool_s, cnt_g);
        k_gemm<<<dim3(NGRAPH / 64, HDIM / 64), 256, 0, stream>>>(pool_s, W3, b3, zcat + s * HDIM,
                                                                 NGRAPH, HDIM, HDIM, 2 * HDIM, 0);
    }

    // MLP head
    k_gemm<<<dim3(NGRAPH / 64, (4 * HDIM) / 64), 256, 0, stream>>>(zcat, Wc1, bc1, z1, NGRAPH, 4 * HDIM, 2 * HDIM, 4 * HDIM, 1);
    k_gemm<<<dim3(NGRAPH / 64, (2 * HDIM) / 64), 256, 0, stream>>>(z1, Wc2, bc2, z2, NGRAPH, 2 * HDIM, 4 * HDIM, 2 * HDIM, 1);
    k_gemm<<<dim3(NGRAPH / 64, 1), 256, 0, stream>>>(z2, Wc3, bc3, out, NGRAPH, OUTC, 2 * HDIM, OUTC, 0);
}